// Round 3
// baseline (463.455 us; speedup 1.0000x reference)
//
#include <hip/hip_runtime.h>

#define C_DIM 256
#define K_CODES 1024
#define HW 1024
#define TOK_PER_BLK 64
#define LDS_STRIDE 260   // floats per LDS row (256 data + pad; %4==0 for float4 align)
#define N_TOK 32768
#define OUT0_ELEMS 8388608

// ---------------------------------------------------------------------------
// Kernel B: per-code squared norms |w_k|^2, numpy-pairwise order (f32).
// ---------------------------------------------------------------------------
__global__ void bk_kernel(const float* __restrict__ cb, float* __restrict__ Bk) {
#pragma clang fp contract(off)
    int k = blockIdx.x * blockDim.x + threadIdx.x;
    if (k >= K_CODES) return;
    const float* w = cb + k * C_DIM;
    float s[2];
    for (int h = 0; h < 2; ++h) {
        const float* p = w + h * 128;
        float r[8];
        #pragma unroll
        for (int j = 0; j < 8; ++j) { float v = p[j]; r[j] = v * v; }
        for (int i = 8; i < 128; i += 8) {
            #pragma unroll
            for (int j = 0; j < 8; ++j) { float v = p[i + j]; r[j] = r[j] + v * v; }
        }
        s[h] = ((r[0] + r[1]) + (r[2] + r[3])) + ((r[4] + r[5]) + (r[6] + r[7]));
    }
    Bk[k] = s[0] + s[1];
}

// ---------------------------------------------------------------------------
// Kernel A: per 64-token tile: argmin over 1024 codes + gather + ST output +
// loss partial. 256 threads = 4 waves; wave g owns codes [g*256, g*256+256).
// ---------------------------------------------------------------------------
__global__ __launch_bounds__(256, 2) void vq_kernel(
        const float* __restrict__ z, const float* __restrict__ cb,
        const float* __restrict__ Bk, float* __restrict__ out0,
        float* __restrict__ out_idx, double* __restrict__ loss_acc) {
#pragma clang fp contract(off)
    __shared__ float  zt[TOK_PER_BLK * LDS_STRIDE];
    __shared__ float  bv[256];
    __shared__ int    bi[256];
    __shared__ int    fi[TOK_PER_BLK];
    __shared__ double red[256];

    const int tid = threadIdx.x;
    const int blk = blockIdx.x;
    const int b   = blk >> 4;                 // 16 blocks per batch image
    const int hw0 = (blk & 15) * TOK_PER_BLK;
    const long zbase = (long)b * (C_DIM * HW) + hw0;

    // ---- stage z tile into LDS transposed: zt[hw][c] ----
    for (int t = 0; t < 16; ++t) {
        int L = t * 256 + tid;                // float4 index, 0..4095
        int c = L >> 4;                       // 16 float4 per channel row
        int q = L & 15;
        const float4 v = *(const float4*)&z[zbase + (long)c * HW + q * 4];
        int hw = q * 4;
        zt[(hw + 0) * LDS_STRIDE + c] = v.x;
        zt[(hw + 1) * LDS_STRIDE + c] = v.y;
        zt[(hw + 2) * LDS_STRIDE + c] = v.z;
        zt[(hw + 3) * LDS_STRIDE + c] = v.w;
    }
    __syncthreads();

    const int tt = tid & 63;                  // my token within tile
    const float* zrow = &zt[tt * LDS_STRIDE];

    // ---- A = |z|^2 in numpy pairwise order (f32, no contraction) ----
    float A;
    {
        float s[2];
        for (int h = 0; h < 2; ++h) {
            const float* p = zrow + h * 128;
            float r[8];
            #pragma unroll
            for (int j = 0; j < 8; ++j) { float v = p[j]; r[j] = v * v; }
            for (int i = 8; i < 128; i += 8) {
                #pragma unroll
                for (int j = 0; j < 8; ++j) { float v = p[i + j]; r[j] = r[j] + v * v; }
            }
            s[h] = ((r[0] + r[1]) + (r[2] + r[3])) + ((r[4] + r[5]) + (r[6] + r[7]));
        }
        A = s[0] + s[1];
    }

    // ---- scan my wave's 256 codes, 16 at a time (ILP + scalar w loads) ----
    const int g = __builtin_amdgcn_readfirstlane(tid >> 6);  // wave id, uniform
    float best = 3.4e38f;
    int   bidx = 0;
    for (int kb = 0; kb < 16; ++kb) {
        const int kbase = g * 256 + kb * 16;
        const float* wbase = cb + (long)kbase * C_DIM;
        float acc[16];
        #pragma unroll
        for (int j = 0; j < 16; ++j) acc[j] = 0.0f;
        for (int c = 0; c < 256; c += 4) {
            const float4 zv = *(const float4*)&zrow[c];
            #pragma unroll
            for (int j = 0; j < 16; ++j) {
                const float* wr = wbase + j * C_DIM + c;   // wave-uniform -> s_load
                acc[j] = fmaf(zv.x, wr[0], acc[j]);
                acc[j] = fmaf(zv.y, wr[1], acc[j]);
                acc[j] = fmaf(zv.z, wr[2], acc[j]);
                acc[j] = fmaf(zv.w, wr[3], acc[j]);
            }
        }
        #pragma unroll
        for (int j = 0; j < 16; ++j) {
            float s = A + Bk[kbase + j];            // fl(A + B_k)
            float d = fmaf(-2.0f, acc[j], s);       // fl(s - 2*dot), one rounding
            if (d < best) { best = d; bidx = kbase + j; }   // strict <, ascending k
        }
    }

    // ---- cross-wave argmin (ascending g preserves lowest-k tie-break) ----
    bv[tid] = best; bi[tid] = bidx;
    __syncthreads();
    if (tid < 64) {
        float bb = bv[tid]; int ii = bi[tid];
        for (int gg = 1; gg < 4; ++gg) {
            float v = bv[gg * 64 + tid];
            if (v < bb) { bb = v; ii = bi[gg * 64 + tid]; }
        }
        fi[tid] = ii;
        out_idx[blk * 64 + tid] = (float)ii;      // token t = blk*64 + tt
    }
    __syncthreads();

    // ---- gather z_q, straight-through out0 = fl(z + fl(w - z)), loss ----
    const int myidx = fi[tt];
    const float* wrow = cb + (long)myidx * C_DIM;
    const int c0 = (tid >> 6) * 64;               // each wave covers 64 channels
    double lsum = 0.0;
    for (int cc = 0; cc < 64; cc += 4) {
        const int c = c0 + cc;
        const float4 wv = *(const float4*)&wrow[c];
        float z0 = zrow[c], z1 = zrow[c + 1], z2 = zrow[c + 2], z3 = zrow[c + 3];
        float t0 = wv.x - z0, t1 = wv.y - z1, t2 = wv.z - z2, t3 = wv.w - z3;
        out0[zbase + (long)(c + 0) * HW + tt] = z0 + t0;
        out0[zbase + (long)(c + 1) * HW + tt] = z1 + t1;
        out0[zbase + (long)(c + 2) * HW + tt] = z2 + t2;
        out0[zbase + (long)(c + 3) * HW + tt] = z3 + t3;
        float q0 = t0 * t0, q1 = t1 * t1, q2 = t2 * t2, q3 = t3 * t3;
        lsum += (double)q0 + (double)q1 + (double)q2 + (double)q3;
    }
    red[tid] = lsum;
    __syncthreads();
    if (tid == 0) {
        double s = 0.0;
        for (int i = 0; i < 256; ++i) s += red[i];
        atomicAdd(loss_acc, s);
    }
}

// ---------------------------------------------------------------------------
// Kernel C: finalize loss = (1 + 0.25) * mean((zq - z)^2)
// ---------------------------------------------------------------------------
__global__ void loss_kernel(const double* __restrict__ acc, float* __restrict__ out_loss) {
    double mse = acc[0] / (double)OUT0_ELEMS;
    out_loss[0] = (float)(mse + 0.25 * mse);
}

extern "C" void kernel_launch(void* const* d_in, const int* in_sizes, int n_in,
                              void* d_out, int out_size, void* d_ws, size_t ws_size,
                              hipStream_t stream) {
    const float* z  = (const float*)d_in[0];
    const float* cb = (const float*)d_in[1];
    float* out      = (float*)d_out;
    float* out_idx  = out + OUT0_ELEMS;
    float* out_loss = out + OUT0_ELEMS + N_TOK;
    double* lacc    = (double*)d_ws;
    float*  Bk      = (float*)((char*)d_ws + 64);

    hipMemsetAsync(d_ws, 0, 64, stream);
    bk_kernel<<<4, 256, 0, stream>>>(cb, Bk);
    vq_kernel<<<512, 256, 0, stream>>>(z, cb, Bk, out, out_idx, lacc);
    loss_kernel<<<1, 1, 0, stream>>>(lacc, out_loss);
}

// Round 5
// 380.034 us; speedup vs baseline: 1.2195x; 1.2195x over previous
//
#include <hip/hip_runtime.h>

#define C_DIM 256
#define K_CODES 1024
#define HW 1024
#define TOK_PER_BLK 64
#define LDS_STRIDE 260   // floats per LDS row (256 data + pad; %4==0 for float4 align)
#define N_TOK 32768
#define OUT0_ELEMS 8388608

// ---------------------------------------------------------------------------
// Kernel B: per-code squared norms |w_k|^2, numpy-pairwise order (f32).
// ---------------------------------------------------------------------------
__global__ void bk_kernel(const float* __restrict__ cb, float* __restrict__ Bk) {
#pragma clang fp contract(off)
    int k = blockIdx.x * blockDim.x + threadIdx.x;
    if (k >= K_CODES) return;
    const float* w = cb + k * C_DIM;
    float s[2];
    for (int h = 0; h < 2; ++h) {
        const float* p = w + h * 128;
        float r[8];
        #pragma unroll
        for (int j = 0; j < 8; ++j) { float v = p[j]; r[j] = v * v; }
        for (int i = 8; i < 128; i += 8) {
            #pragma unroll
            for (int j = 0; j < 8; ++j) { float v = p[i + j]; r[j] = r[j] + v * v; }
        }
        s[h] = ((r[0] + r[1]) + (r[2] + r[3])) + ((r[4] + r[5]) + (r[6] + r[7]));
    }
    Bk[k] = s[0] + s[1];
}

// ---------------------------------------------------------------------------
// Kernel A: per 64-token tile: argmin over 1024 codes + gather + ST output +
// loss partial. 512 threads = 8 waves; wave g owns codes [g*128, g*128+128).
// ---------------------------------------------------------------------------
__global__ __launch_bounds__(512, 4) void vq_kernel(
        const float* __restrict__ z, const float* __restrict__ cb,
        const float* __restrict__ Bk, float* __restrict__ out0,
        float* __restrict__ out_idx, double* __restrict__ loss_acc) {
#pragma clang fp contract(off)
    __shared__ float  zt[TOK_PER_BLK * LDS_STRIDE];
    __shared__ float  bv[512];
    __shared__ int    bi[512];
    __shared__ int    fi[TOK_PER_BLK];
    __shared__ double red[512];

    const int tid = threadIdx.x;
    const int blk = blockIdx.x;
    const int b   = blk >> 4;                 // 16 blocks per batch image
    const int hw0 = (blk & 15) * TOK_PER_BLK;
    const long zbase = (long)b * (C_DIM * HW) + hw0;

    // ---- stage z tile into LDS transposed: zt[hw][c] ----
    for (int t = 0; t < 8; ++t) {
        int L = t * 512 + tid;                // float4 index, 0..4095
        int c = L >> 4;                       // 16 float4 per channel row
        int q = L & 15;
        const float4 v = *(const float4*)&z[zbase + (long)c * HW + q * 4];
        int hw = q * 4;
        zt[(hw + 0) * LDS_STRIDE + c] = v.x;
        zt[(hw + 1) * LDS_STRIDE + c] = v.y;
        zt[(hw + 2) * LDS_STRIDE + c] = v.z;
        zt[(hw + 3) * LDS_STRIDE + c] = v.w;
    }
    __syncthreads();

    const int tt = tid & 63;                  // my token within tile
    const float* zrow = &zt[tt * LDS_STRIDE];

    // ---- A = |z|^2 in numpy pairwise order (f32, no contraction) ----
    float A;
    {
        float s[2];
        for (int h = 0; h < 2; ++h) {
            const float* p = zrow + h * 128;
            float r[8];
            #pragma unroll
            for (int j = 0; j < 8; ++j) { float v = p[j]; r[j] = v * v; }
            for (int i = 8; i < 128; i += 8) {
                #pragma unroll
                for (int j = 0; j < 8; ++j) { float v = p[i + j]; r[j] = r[j] + v * v; }
            }
            s[h] = ((r[0] + r[1]) + (r[2] + r[3])) + ((r[4] + r[5]) + (r[6] + r[7]));
        }
        A = s[0] + s[1];
    }

    // ---- scan my wave's 128 codes, 16 at a time (ILP + scalar w loads) ----
    const int g = __builtin_amdgcn_readfirstlane(tid >> 6);  // wave id, uniform
    float best = 3.4e38f;
    int   bidx = 0;
    for (int kb = 0; kb < 8; ++kb) {
        const int kbase = g * 128 + kb * 16;
        const float* wbase = cb + (long)kbase * C_DIM;
        float acc[16];
        #pragma unroll
        for (int j = 0; j < 16; ++j) acc[j] = 0.0f;
        for (int c = 0; c < 256; c += 4) {
            const float4 zv = *(const float4*)&zrow[c];
            #pragma unroll
            for (int j = 0; j < 16; ++j) {
                const float* wr = wbase + j * C_DIM + c;   // wave-uniform -> s_load
                acc[j] = fmaf(zv.x, wr[0], acc[j]);
                acc[j] = fmaf(zv.y, wr[1], acc[j]);
                acc[j] = fmaf(zv.z, wr[2], acc[j]);
                acc[j] = fmaf(zv.w, wr[3], acc[j]);
            }
        }
        #pragma unroll
        for (int j = 0; j < 16; ++j) {
            float s = A + Bk[kbase + j];            // fl(A + B_k)
            float d = fmaf(-2.0f, acc[j], s);       // fl(s - 2*dot), one rounding
            if (d < best) { best = d; bidx = kbase + j; }   // strict <, ascending k
        }
    }

    // ---- cross-wave argmin (ascending g preserves lowest-k tie-break) ----
    bv[tid] = best; bi[tid] = bidx;
    __syncthreads();
    if (tid < 64) {
        float bb = bv[tid]; int ii = bi[tid];
        for (int gg = 1; gg < 8; ++gg) {
            float v = bv[gg * 64 + tid];
            if (v < bb) { bb = v; ii = bi[gg * 64 + tid]; }
        }
        fi[tid] = ii;
        out_idx[blk * 64 + tid] = (float)ii;      // token t = blk*64 + tt
    }
    __syncthreads();

    // ---- gather z_q, straight-through out0 = fl(z + fl(w - z)), loss ----
    const int myidx = fi[tt];
    const float* wrow = cb + (long)myidx * C_DIM;
    const int c0 = (tid >> 6) * 32;               // each wave covers 32 channels
    double lsum = 0.0;
    for (int cc = 0; cc < 32; cc += 4) {
        const int c = c0 + cc;
        const float4 wv = *(const float4*)&wrow[c];
        float z0 = zrow[c], z1 = zrow[c + 1], z2 = zrow[c + 2], z3 = zrow[c + 3];
        float t0 = wv.x - z0, t1 = wv.y - z1, t2 = wv.z - z2, t3 = wv.w - z3;
        out0[zbase + (long)(c + 0) * HW + tt] = z0 + t0;
        out0[zbase + (long)(c + 1) * HW + tt] = z1 + t1;
        out0[zbase + (long)(c + 2) * HW + tt] = z2 + t2;
        out0[zbase + (long)(c + 3) * HW + tt] = z3 + t3;
        float q0 = t0 * t0, q1 = t1 * t1, q2 = t2 * t2, q3 = t3 * t3;
        lsum += (double)q0 + (double)q1 + (double)q2 + (double)q3;
    }
    red[tid] = lsum;
    __syncthreads();
    if (tid == 0) {
        double s = 0.0;
        for (int i = 0; i < 512; ++i) s += red[i];
        atomicAdd(loss_acc, s);
    }
}

// ---------------------------------------------------------------------------
// Kernel C: finalize loss = (1 + 0.25) * mean((zq - z)^2)
// ---------------------------------------------------------------------------
__global__ void loss_kernel(const double* __restrict__ acc, float* __restrict__ out_loss) {
    double mse = acc[0] / (double)OUT0_ELEMS;
    out_loss[0] = (float)(mse + 0.25 * mse);
}

extern "C" void kernel_launch(void* const* d_in, const int* in_sizes, int n_in,
                              void* d_out, int out_size, void* d_ws, size_t ws_size,
                              hipStream_t stream) {
    const float* z  = (const float*)d_in[0];
    const float* cb = (const float*)d_in[1];
    float* out      = (float*)d_out;
    float* out_idx  = out + OUT0_ELEMS;
    float* out_loss = out + OUT0_ELEMS + N_TOK;
    double* lacc    = (double*)d_ws;
    float*  Bk      = (float*)((char*)d_ws + 64);

    hipMemsetAsync(d_ws, 0, 64, stream);
    bk_kernel<<<4, 256, 0, stream>>>(cb, Bk);
    vq_kernel<<<512, 512, 0, stream>>>(z, cb, Bk, out, out_idx, lacc);
    loss_kernel<<<1, 1, 0, stream>>>(lacc, out_loss);
}

// Round 6
// 156.648 us; speedup vs baseline: 2.9586x; 2.4260x over previous
//
#include <hip/hip_runtime.h>

typedef __attribute__((ext_vector_type(8))) short bf16x8;
typedef __attribute__((ext_vector_type(4))) float f32x4;

#define C_DIM 256
#define K_CODES 1024
#define HW 1024
#define N_TOK 32768
#define OUT0_ELEMS 8388608
#define MARGIN 2e-3f
#define NSLOT 24

static __device__ __forceinline__ unsigned short f2bf(float f) {
    unsigned u = __float_as_uint(f);
    unsigned r = (u + 0x7FFFu + ((u >> 16) & 1u)) >> 16;
    return (unsigned short)r;
}

// ---------------------------------------------------------------------------
// Bk: per-code |w|^2, numpy-pairwise f32 (unchanged from passing kernel).
// ---------------------------------------------------------------------------
__global__ void bk_kernel(const float* __restrict__ cb, float* __restrict__ Bk) {
#pragma clang fp contract(off)
    int k = blockIdx.x * blockDim.x + threadIdx.x;
    if (k >= K_CODES) return;
    const float* w = cb + k * C_DIM;
    float s[2];
    for (int h = 0; h < 2; ++h) {
        const float* p = w + h * 128;
        float r[8];
        #pragma unroll
        for (int j = 0; j < 8; ++j) { float v = p[j]; r[j] = v * v; }
        for (int i = 8; i < 128; i += 8) {
            #pragma unroll
            for (int j = 0; j < 8; ++j) { float v = p[i + j]; r[j] = r[j] + v * v; }
        }
        s[h] = ((r[0] + r[1]) + (r[2] + r[3])) + ((r[4] + r[5]) + (r[6] + r[7]));
    }
    Bk[k] = s[0] + s[1];
}

// ---------------------------------------------------------------------------
// cb -> bf16 copy [K][C]
// ---------------------------------------------------------------------------
__global__ __launch_bounds__(64) void cbh_kernel(const float* __restrict__ cb,
                                                 unsigned short* __restrict__ cb_h) {
    int k = blockIdx.x, l = threadIdx.x;
    const float4 v = *(const float4*)&cb[k * C_DIM + l * 4];
    ushort4 o;
    o.x = f2bf(v.x); o.y = f2bf(v.y); o.z = f2bf(v.z); o.w = f2bf(v.w);
    *(ushort4*)&cb_h[k * C_DIM + l * 4] = o;
}

// ---------------------------------------------------------------------------
// z prep: NCHW f32 -> z_t f32 [N][C] (stored in d_out region, overwritten
// later by out_kernel), z_h bf16 [N][C], A[N] = |z|^2 numpy-pairwise.
// ---------------------------------------------------------------------------
__global__ __launch_bounds__(256) void zprep_kernel(const float* __restrict__ z,
        float* __restrict__ z_t, unsigned short* __restrict__ z_h,
        float* __restrict__ A) {
#pragma clang fp contract(off)
    __shared__ float tile[64 * 257];
    const int t = threadIdx.x, blk = blockIdx.x;
    const int b = blk >> 4, hw0 = (blk & 15) * 64, tok0 = blk * 64;
    const size_t zb = (size_t)b * (C_DIM * HW) + hw0;
    for (int i = 0; i < 64; ++i) {
        int pos = i * 256 + t;
        int c = pos >> 6, hw = pos & 63;
        tile[hw * 257 + c] = z[zb + (size_t)c * HW + hw];
    }
    __syncthreads();
    if (t < 64) {
        const float* p0 = &tile[t * 257];
        float s[2];
        for (int h = 0; h < 2; ++h) {
            const float* p = p0 + h * 128;
            float r[8];
            #pragma unroll
            for (int j = 0; j < 8; ++j) { float v = p[j]; r[j] = v * v; }
            for (int i = 8; i < 128; i += 8) {
                #pragma unroll
                for (int j = 0; j < 8; ++j) { float v = p[i + j]; r[j] = r[j] + v * v; }
            }
            s[h] = ((r[0] + r[1]) + (r[2] + r[3])) + ((r[4] + r[5]) + (r[6] + r[7]));
        }
        A[tok0 + t] = s[0] + s[1];
    }
    for (int i = 0; i < 64; ++i) {
        int pos = i * 256 + t;
        int tl = pos >> 8, c = pos & 255;
        float v = tile[tl * 257 + c];
        z_t[(size_t)(tok0 + tl) * 256 + c] = v;
        z_h[(size_t)(tok0 + tl) * 256 + c] = f2bf(v);
    }
}

// ---------------------------------------------------------------------------
// Main: per 64-token block. Sweep 1: bf16 MFMA est distances -> per-token min.
// Sweep 2: collect candidates within MARGIN. Then exact f32 rescore (bit-
// identical to the previously passing kernel's arithmetic) -> idx.
// 256 thr = 4 waves; wave w owns col-tile ct=w of each 64-code chunk.
// ---------------------------------------------------------------------------
__global__ __launch_bounds__(256, 2) void vq_main(
        const unsigned short* __restrict__ z_h, const unsigned short* __restrict__ cb_h,
        const float* __restrict__ A, const float* __restrict__ Bk,
        const float* __restrict__ z_t, const float* __restrict__ cb,
        float* __restrict__ out_idx) {
#pragma clang fp contract(off)
    __shared__ __align__(16) char zs[32768];
    __shared__ __align__(16) char wsm[32768];
    __shared__ float minv4[64][4];
    __shared__ int   cnt[64];
    __shared__ int   ck[64 * NSLOT];
    __shared__ float cd[64 * NSLOT];

    const int tid = threadIdx.x;
    const int w = tid >> 6, l = tid & 63;
    const int lq = l >> 4, lr = l & 15;
    const int tok0 = blockIdx.x * 64;

    // stage z tile (64 tok x 256 c bf16), layout [c8][tok] 16B units, XOR-swz
    for (int i = 0; i < 8; ++i) {
        int unit = i * 256 + tid;
        int tok = unit >> 5, c8 = unit & 31;
        uint4 v = *(const uint4*)(z_h + (size_t)(tok0 + tok) * 256 + c8 * 8);
        *(uint4*)(zs + c8 * 1024 + ((tok * 16) ^ ((c8 & 7) << 4))) = v;
    }
    if (tid < 64) cnt[tid] = 0;
    __syncthreads();

    // hoist A-fragments: afr[rt][cs]; lane holds z[rt*16+lr][cs*32+lq*8 ..+8]
    bf16x8 afr[4][8];
    #pragma unroll
    for (int rt = 0; rt < 4; ++rt)
        #pragma unroll
        for (int cs = 0; cs < 8; ++cs) {
            int tok = rt * 16 + lr;
            int c8 = cs * 4 + lq;
            afr[rt][cs] = *(const bf16x8*)(zs + c8 * 1024 + ((tok * 16) ^ ((c8 & 7) << 4)));
        }

    float A_l[16];
    #pragma unroll
    for (int s = 0; s < 16; ++s)
        A_l[s] = A[tok0 + (s >> 2) * 16 + lq * 4 + (s & 3)];

    float bmin[16], mv[16];
    #pragma unroll
    for (int s = 0; s < 16; ++s) { bmin[s] = 3.4e38f; mv[s] = 3.4e38f; }

    for (int sweep = 0; sweep < 2; ++sweep) {
        for (int kc = 0; kc < 16; ++kc) {
            __syncthreads();
            // stage 64-code chunk of bf16 codebook, same layout/swizzle
            for (int i = 0; i < 8; ++i) {
                int unit = i * 256 + tid;
                int code = unit >> 5, c8 = unit & 31;
                uint4 v = *(const uint4*)(cb_h + (size_t)(kc * 64 + code) * 256 + c8 * 8);
                *(uint4*)(wsm + c8 * 1024 + ((code * 16) ^ ((c8 & 7) << 4))) = v;
            }
            __syncthreads();
            const int kcode = kc * 64 + w * 16 + lr;   // this lane's code column
            const float bkv = Bk[kcode];
            f32x4 acc[4];
            #pragma unroll
            for (int rt = 0; rt < 4; ++rt) acc[rt] = (f32x4){0.f, 0.f, 0.f, 0.f};
            #pragma unroll
            for (int cs = 0; cs < 8; ++cs) {
                int c8 = cs * 4 + lq;
                int codeb = w * 16 + lr;
                bf16x8 bfr = *(const bf16x8*)(wsm + c8 * 1024 + ((codeb * 16) ^ ((c8 & 7) << 4)));
                #pragma unroll
                for (int rt = 0; rt < 4; ++rt)
                    acc[rt] = __builtin_amdgcn_mfma_f32_16x16x32_bf16(afr[rt][cs], bfr, acc[rt], 0, 0, 0);
            }
            if (sweep == 0) {
                #pragma unroll
                for (int s = 0; s < 16; ++s) {
                    float est = fmaf(-2.0f, acc[s >> 2][s & 3], A_l[s] + bkv);
                    bmin[s] = fminf(bmin[s], est);
                }
            } else {
                #pragma unroll
                for (int s = 0; s < 16; ++s) {
                    float est = fmaf(-2.0f, acc[s >> 2][s & 3], A_l[s] + bkv);
                    if (est <= mv[s] + MARGIN) {
                        int tl = (s >> 2) * 16 + lq * 4 + (s & 3);
                        int pos = atomicAdd(&cnt[tl], 1);
                        if (pos < NSLOT) ck[tl * NSLOT + pos] = kcode;
                    }
                }
            }
        }
        if (sweep == 0) {
            // reduce slot-mins over the 16 lanes sharing each token
            #pragma unroll
            for (int s = 0; s < 16; ++s) {
                float v = bmin[s];
                #pragma unroll
                for (int m = 1; m < 16; m <<= 1) v = fminf(v, __shfl_xor(v, m));
                if (lr == 0) minv4[(s >> 2) * 16 + lq * 4 + (s & 3)][w] = v;
            }
            __syncthreads();
            #pragma unroll
            for (int s = 0; s < 16; ++s) {
                int tl = (s >> 2) * 16 + lq * 4 + (s & 3);
                mv[s] = fminf(fminf(minv4[tl][0], minv4[tl][1]),
                              fminf(minv4[tl][2], minv4[tl][3]));
            }
            __syncthreads();
        }
    }
    __syncthreads();

    // exact rescore of candidates (identical arithmetic to the passing kernel)
    {
        int tl = tid >> 2;
        int n = min(cnt[tl], NSLOT);
        const float* zr = z_t + (size_t)(tok0 + tl) * 256;
        float Ag = A[tok0 + tl];
        for (int s = tid & 3; s < n; s += 4) {
            int k = ck[tl * NSLOT + s];
            const float* wr = cb + (size_t)k * 256;
            float acc = 0.0f;
            for (int c = 0; c < 256; c += 4) {
                float4 zv = *(const float4*)&zr[c];
                float4 wv = *(const float4*)&wr[c];
                acc = fmaf(zv.x, wv.x, acc);
                acc = fmaf(zv.y, wv.y, acc);
                acc = fmaf(zv.z, wv.z, acc);
                acc = fmaf(zv.w, wv.w, acc);
            }
            cd[tl * NSLOT + s] = fmaf(-2.0f, acc, Ag + Bk[k]);
        }
    }
    __syncthreads();
    if (tid < 64) {
        int n = cnt[tid];
        float bd = 3.4e38f; int bki = 0x7fffffff;
        if (n <= NSLOT) {
            for (int s = 0; s < n; ++s) {
                float d = cd[tid * NSLOT + s]; int k = ck[tid * NSLOT + s];
                if (d < bd || (d == bd && k < bki)) { bd = d; bki = k; }
            }
        } else {
            // overflow fallback (statistically never): exact scan of all codes
            const float* zr = z_t + (size_t)(tok0 + tid) * 256;
            float Ag = A[tok0 + tid];
            for (int k = 0; k < K_CODES; ++k) {
                const float* wr = cb + (size_t)k * 256;
                float acc = 0.0f;
                for (int c = 0; c < 256; c += 4) {
                    float4 zv = *(const float4*)&zr[c];
                    float4 wv = *(const float4*)&wr[c];
                    acc = fmaf(zv.x, wv.x, acc);
                    acc = fmaf(zv.y, wv.y, acc);
                    acc = fmaf(zv.z, wv.z, acc);
                    acc = fmaf(zv.w, wv.w, acc);
                }
                float d = fmaf(-2.0f, acc, Ag + Bk[k]);
                if (d < bd) { bd = d; bki = k; }
            }
        }
        out_idx[tok0 + tid] = (float)bki;
    }
}

// ---------------------------------------------------------------------------
// Output: out0 = z + (w - z) elementwise (NCHW), loss partials.
// ---------------------------------------------------------------------------
__global__ __launch_bounds__(256, 2) void out_kernel(const float* __restrict__ z,
        const float* __restrict__ cb, const float* __restrict__ out_idx_f,
        float* __restrict__ out0, double* __restrict__ lacc) {
#pragma clang fp contract(off)
    __shared__ float wl[64 * 257];
    __shared__ int fi[64];
    __shared__ double red[256];
    const int t = threadIdx.x, blk = blockIdx.x;
    const int b = blk >> 4, hw0 = (blk & 15) * 64;
    const size_t zb = (size_t)b * (C_DIM * HW) + hw0;
    if (t < 64) fi[t] = (int)out_idx_f[blk * 64 + t];
    __syncthreads();
    for (int i = 0; i < 64; ++i) {
        int pos = i * 256 + t;
        int row = pos >> 8, c = pos & 255;
        wl[row * 257 + c] = cb[(size_t)fi[row] * 256 + c];
    }
    __syncthreads();
    double lsum = 0.0;
    for (int i = 0; i < 64; ++i) {
        int pos = i * 256 + t;
        int c = pos >> 6, hw = pos & 63;
        float zv = z[zb + (size_t)c * HW + hw];
        float wv = wl[hw * 257 + c];
        float d = wv - zv;
        out0[zb + (size_t)c * HW + hw] = zv + d;
        float q = d * d;
        lsum += (double)q;
    }
    red[t] = lsum;
    __syncthreads();
    if (t == 0) {
        double s = 0.0;
        for (int i = 0; i < 256; ++i) s += red[i];
        atomicAdd(lacc, s);
    }
}

__global__ void loss_kernel(const double* __restrict__ acc, float* __restrict__ out_loss) {
    double mse = acc[0] / (double)OUT0_ELEMS;
    out_loss[0] = (float)(mse + 0.25 * mse);
}

extern "C" void kernel_launch(void* const* d_in, const int* in_sizes, int n_in,
                              void* d_out, int out_size, void* d_ws, size_t ws_size,
                              hipStream_t stream) {
    const float* z  = (const float*)d_in[0];
    const float* cb = (const float*)d_in[1];
    float* out      = (float*)d_out;
    float* out_idx  = out + OUT0_ELEMS;
    float* out_loss = out + OUT0_ELEMS + N_TOK;

    char* wsb = (char*)d_ws;
    double*         lacc = (double*)wsb;                       // 64 B
    float*          Bk   = (float*)(wsb + 64);                 // 4 KB
    float*          A    = (float*)(wsb + 8192);               // 128 KB
    unsigned short* cb_h = (unsigned short*)(wsb + 262144);    // 512 KB
    unsigned short* z_h  = (unsigned short*)(wsb + 1048576);   // 16 MB
    float*          z_t  = out;  // reuse out0 region as [N][C] f32 scratch

    hipMemsetAsync(d_ws, 0, 64, stream);
    zprep_kernel<<<512, 256, 0, stream>>>(z, z_t, z_h, A);
    bk_kernel<<<4, 256, 0, stream>>>(cb, Bk);
    cbh_kernel<<<1024, 64, 0, stream>>>(cb, cb_h);
    vq_main<<<512, 256, 0, stream>>>(z_h, cb_h, A, Bk, z_t, cb, out_idx);
    out_kernel<<<512, 256, 0, stream>>>(z, cb, out_idx, out, lacc);
    loss_kernel<<<1, 1, 0, stream>>>(lacc, out_loss);
}